// Round 7
// baseline (1150.288 us; speedup 1.0000x reference)
//
#include <hip/hip_runtime.h>

#define WID 224
#define HGT 224
#define HWp 50176          // 224*224
#define CHW 150528         // 3*HWp
#define NB  64
#define NSL 2048           // 64 images x 32 slices
#define SCH 1568           // HWp/32
#define NT  9408           // 64*147 tiles of 1024 px
#define TPI 147            // tiles per image
#define TPC 49             // tiles per channel
#define ST0 1552           // stats0/img: [0]=mu_raw,[1..3]lo_raw,[4..6]hi_raw,[16..784)lutA,[784..1552)lutB
#define ST1 784            // stats1/img: [0]=mu,[1..3]lo,[4..6]hi,[16..784)lut

// int-offsets (4B units from ws base)
#define OFF_CNTG   0
#define OFF_CNT0   64      // 64 counters
#define OFF_CNT1   128     // 64 counters -> ints[128..192)
#define OFF_HIST1  256     // 64*768 ints
// float-offsets
#define OFF_SCALE  49408
#define OFF_PMAXA  49472   // 2048
#define OFF_PSUM0  51520   // 2048
#define OFF_PMIN0  53568   // 6144
#define OFF_PMAX0  59712   // 6144
#define OFF_PHIST0 65856   // ints: 2048*1536
#define OFF_PSUM1  3211584 // 9408
#define OFF_PMIN1  3220992 // 9408
#define OFF_PMAX1  3230400 // 9408
#define OFF_ST0    3239808 // 64*1552
#define OFF_ST1    3339136 // 64*784
#define OFF_INTER  3389312 // 9,633,792 floats

__device__ __forceinline__ float clip255(float v){ return fminf(fmaxf(v, 0.f), 255.f); }

__device__ __forceinline__ float blk_reduce(float v, float* red, int tid, int op){
    red[tid] = v; __syncthreads();
    for (int s = 128; s > 0; s >>= 1){
        if (tid < s){
            float a = red[tid], b = red[tid+s];
            red[tid] = (op==0) ? a+b : (op==1 ? fminf(a,b) : fmaxf(a,b));
        }
        __syncthreads();
    }
    float r = red[0]; __syncthreads();
    return r;
}

__device__ __forceinline__ void build_lut(const int* h, float* lut){
    int step = (HWp - h[255]) / 255;
    int cum = 0;                                   // exclusive cumsum
    for (int i = 0; i < 256; i++){
        int l = (step > 0) ? min(max((cum + (step >> 1)) / step, 0), 255) : i;
        lut[i] = (float)l;
        cum += h[i];
    }
}

__device__ __forceinline__ float samp(const float* __restrict__ pl, float yi, float xi, float scl){
    if (xi < 0.f || xi > (float)(WID-1) || yi < 0.f || yi > (float)(HGT-1)) return 0.f;
    return pl[(int)yi * WID + (int)xi] * scl;
}

// Compute 4 output px for plane-offset p of channel c; stats already resolved (mu/lo/hi scaled, lut selected).
__device__ __forceinline__ void apply_body(const float* __restrict__ img,
                                           int c, int p,
                                           int j, int ap, float m, float scl,
                                           float mu, float lo, float hi,
                                           const float* __restrict__ lut,
                                           float o[4])
{
    int y = p / WID;
    int x = p - y*WID;
    const float* pl = img + c*HWp;
    float4 v4 = *(const float4*)(pl + p);
    float iv[4] = {v4.x*scl, v4.y*scl, v4.z*scl, v4.w*scl};

    if (!ap) {
        #pragma unroll
        for (int k = 0; k < 4; k++) o[k] = iv[k];
        return;
    }
    switch (j){
    case 0: case 1: case 2: case 3: case 4: {   // affine family
        float a = 1.f, bb = 0.f, cc = 0.f, dd = 0.f, ee = 1.f, ff = 0.f;
        if (j == 0)      bb = -0.3f + 0.6f*m;
        else if (j == 1) dd = -0.3f + 0.6f*m;
        else if (j == 2) cc = (-0.45f + 0.9f*m) * (float)WID;
        else if (j == 3) ff = (-0.45f + 0.9f*m) * (float)HGT;
        else {
            float deg = -30.f + 60.f*m;
            float rad = deg * (float)(3.14159265358979323846/180.0);
            float cs = cosf(rad), sn = sinf(rad);
            float cx = (WID-1)*0.5f, cy = (HGT-1)*0.5f;
            a = cs; bb = sn; dd = -sn; ee = cs;
            cc = cx - cs*cx - sn*cy;
            ff = cy + sn*cx - cs*cy;
        }
        float yf = (float)y;
        #pragma unroll
        for (int k = 0; k < 4; k++){
            float xf = (float)(x + k);
            float sx = a*xf + bb*yf + cc;
            float sy = dd*xf + ee*yf + ff;
            float x0f = floorf(sx), y0f = floorf(sy);
            float wx = sx - x0f, wy = sy - y0f;
            float v00 = samp(pl, y0f,     x0f,     scl);
            float v01 = samp(pl, y0f,     x0f+1.f, scl);
            float v10 = samp(pl, y0f+1.f, x0f,     scl);
            float v11 = samp(pl, y0f+1.f, x0f+1.f, scl);
            float top = v00*(1.f-wx) + v01*wx;
            float bot = v10*(1.f-wx) + v11*wx;
            o[k] = top*(1.f-wy) + bot*wy;
        }
        break; }
    case 5: {
        float f = 0.1f + 1.8f*m;
        #pragma unroll
        for (int k = 0; k < 4; k++) o[k] = clip255(iv[k]*f);
        break; }
    case 6: {
        float4 r4 = *(const float4*)(img + p);
        float4 g4 = *(const float4*)(img + HWp + p);
        float4 b4 = *(const float4*)(img + 2*HWp + p);
        float rr[4] = {r4.x*scl, r4.y*scl, r4.z*scl, r4.w*scl};
        float gg[4] = {g4.x*scl, g4.y*scl, g4.z*scl, g4.w*scl};
        float bl[4] = {b4.x*scl, b4.y*scl, b4.z*scl, b4.w*scl};
        float f = 0.1f + 1.8f*m;
        #pragma unroll
        for (int k = 0; k < 4; k++){
            float g = 0.299f*rr[k] + 0.587f*gg[k] + 0.114f*bl[k];
            o[k] = clip255(g + f*(iv[k] - g));
        }
        break; }
    case 7: {
        float f = 0.1f + 1.8f*m;
        #pragma unroll
        for (int k = 0; k < 4; k++){
            int xx = x + k;
            if (y == 0 || y == HGT-1 || xx == 0 || xx == WID-1) o[k] = iv[k];
            else {
                int q = p + k;
                float s8 = pl[q-WID-1] + pl[q-WID] + pl[q-WID+1]
                         + pl[q-1]     + pl[q+1]
                         + pl[q+WID-1] + pl[q+WID] + pl[q+WID+1];
                float blur = (s8*scl + 5.f*iv[k]) * (1.f/13.f);
                o[k] = clip255(blur + f*(iv[k] - blur));
            }
        }
        break; }
    case 8: {
        float f = 0.1f + 1.8f*m;
        #pragma unroll
        for (int k = 0; k < 4; k++) o[k] = clip255(mu + f*(iv[k] - mu));
        break; }
    case 9: {
        float thr = 256.f*m;
        #pragma unroll
        for (int k = 0; k < 4; k++) o[k] = (iv[k] < thr) ? iv[k] : 255.f - iv[k];
        break; }
    case 10: {
        float q = exp2f(rintf(4.f*m));
        #pragma unroll
        for (int k = 0; k < 4; k++) o[k] = floorf(iv[k]/q)*q;
        break; }
    case 11: {
        #pragma unroll
        for (int k = 0; k < 4; k++){
            int ivi = min(max((int)rintf(iv[k]), 0), 255);
            o[k] = lut[ivi];
        }
        break; }
    case 12: {
        float sc = 255.f / fmaxf(hi - lo, 1e-6f);
        #pragma unroll
        for (int k = 0; k < 4; k++)
            o[k] = (hi > lo) ? clip255((iv[k] - lo) * sc) : iv[k];
        break; }
    default:
        #pragma unroll
        for (int k = 0; k < 4; k++) o[k] = iv[k];
        break;
    }
}

// ---------------- K0: zero ALL ticket counters (ints[0..256); counters end at 192) ----------------
__global__ void k0_init(float* __restrict__ wsf){
    int* ints = (int*)wsf;
    ints[threadIdx.x] = 0;                      // 256 threads -> ints[0..256)
}

// ---------------- K1: stats0 + gmax over x (2048 blocks) ----------------
__global__ void k1_stats(const float* __restrict__ x, const int* __restrict__ op,
                         const int* __restrict__ mask, float* __restrict__ wsf)
{
    __shared__ float red[256];
    __shared__ int sh[1536];
    __shared__ int tick[2];
    int* ints   = (int*)wsf;
    float* pmaxA = wsf + OFF_PMAXA;
    float* psum0 = wsf + OFF_PSUM0;
    float* pmin0 = wsf + OFF_PMIN0;
    float* pmax0 = wsf + OFF_PMAX0;
    int*   phist0 = (int*)wsf + OFF_PHIST0;
    int*   hist1  = (int*)wsf + OFF_HIST1;

    int blk = blockIdx.x, tid = threadIdx.x;
    // zero hist1 (49152 ints / 2048 blocks = 24 each)
    if (tid < 24) hist1[blk*24 + tid] = 0;

    int b = blk >> 5, s = blk & 31;
    int j = op[b], ap = mask[b];
    bool needSum  = ap && (j == 8);
    bool needMM   = ap && (j == 12);
    bool needHist = ap && (j == 11);
    const float* img = x + (size_t)b * CHW;
    int p0 = s * SCH;
    const float GW[3] = {0.299f, 0.587f, 0.114f};

    float mx = 0.f, gs = 0.f;
    for (int c = 0; c < 3; c++){
        const float* pl = img + c*HWp + p0;
        float lo = 3.4e38f, hi = 0.f, cs = 0.f;
        for (int p = tid*4; p < SCH; p += 1024){
            float4 v = *(const float4*)(pl + p);
            float m4 = fmaxf(fmaxf(v.x, v.y), fmaxf(v.z, v.w));
            mx = fmaxf(mx, m4);
            if (needMM){ hi = fmaxf(hi, m4); lo = fminf(lo, fminf(fminf(v.x,v.y), fminf(v.z,v.w))); }
            if (needSum) cs += (v.x + v.y) + (v.z + v.w);
        }
        if (needSum) gs += GW[c] * cs;
        if (needMM){
            float l = blk_reduce(lo, red, tid, 1);
            if (!tid) pmin0[blk*3 + c] = l;
            float h = blk_reduce(hi, red, tid, 2);
            if (!tid) pmax0[blk*3 + c] = h;
        }
    }
    float bm = blk_reduce(mx, red, tid, 2);
    if (!tid) pmaxA[blk] = bm;
    if (needSum){
        float t = blk_reduce(gs, red, tid, 0);
        if (!tid) psum0[blk] = t;
    }
    if (needHist){
        for (int i = tid; i < 1536; i += 256) sh[i] = 0;
        __syncthreads();
        for (int c = 0; c < 3; c++){
            const float* pl = img + c*HWp + p0;
            for (int p = tid; p < SCH; p += 256){
                float v = pl[p];
                atomicAdd(&sh[c*256 + min(max((int)rintf(v), 0), 255)], 1);
                atomicAdd(&sh[768 + c*256 + min(max((int)rintf(v*255.f), 0), 255)], 1);
            }
        }
        __syncthreads();
        for (int i = tid; i < 1536; i += 256) phist0[blk*1536 + i] = sh[i];
    }

    // release partials, take tickets
    __threadfence();
    __syncthreads();
    if (!tid){
        tick[0] = atomicAdd(&ints[OFF_CNT0 + b], 1);
        tick[1] = atomicAdd(&ints[OFF_CNTG], 1);
    }
    __syncthreads();

    if (tick[1] == NSL-1){                 // global winner: scale
        __threadfence();
        float m = 0.f;
        for (int i = tid; i < NSL; i += 256) m = fmaxf(m, pmaxA[i]);
        float gm = blk_reduce(m, red, tid, 2);
        if (!tid) wsf[OFF_SCALE] = (gm <= 1.0f) ? 255.f : 1.f;
    }
    if (tick[0] == 31 && (needSum || needMM || needHist)){   // per-image winner
        __threadfence();
        float* st = wsf + OFF_ST0 + (size_t)b * ST0;
        if (needSum){
            float t = (tid < 32) ? psum0[b*32 + tid] : 0.f;
            float tot = blk_reduce(t, red, tid, 0);
            if (!tid) st[0] = tot * (1.f/(float)HWp);     // mu_raw
        } else if (needMM){
            for (int c = 0; c < 3; c++){
                float l = (tid < 32) ? pmin0[(b*32 + tid)*3 + c] : 3.4e38f;
                float lr = blk_reduce(l, red, tid, 1);
                if (!tid) st[1+c] = lr;                   // lo_raw
                float h = (tid < 32) ? pmax0[(b*32 + tid)*3 + c] : 0.f;
                float hr = blk_reduce(h, red, tid, 2);
                if (!tid) st[4+c] = hr;                   // hi_raw
            }
        } else {
            for (int i = tid; i < 1536; i += 256){
                int t = 0;
                for (int s2 = 0; s2 < 32; s2++) t += phist0[(b*32 + s2)*1536 + i];
                sh[i] = t;
            }
            __syncthreads();
            if (tid < 3)       build_lut(sh + tid*256,           st + 16  + tid*256);      // lutA (scl=1)
            else if (tid < 6)  build_lut(sh + 768 + (tid-3)*256, st + 784 + (tid-3)*256);  // lutB (scl=255)
        }
    }
}

// ---------------- K2: apply depth 0 (x -> inter) + fused stats1 (9408 blocks) ----------------
__global__ void k2_apply0(const float* __restrict__ x, const float* __restrict__ ra,
                          const int* __restrict__ op, const int* __restrict__ mask,
                          float* __restrict__ wsf)
{
    __shared__ float red[256];
    __shared__ int sh[768];
    __shared__ int tk;
    int* ints  = (int*)wsf;
    int* hist1 = (int*)wsf + OFF_HIST1;
    float* psum1 = wsf + OFF_PSUM1;
    float* pmin1 = wsf + OFF_PMIN1;
    float* pmax1 = wsf + OFF_PMAX1;
    float* inter = wsf + OFF_INTER;

    int t = blockIdx.x, tid = threadIdx.x;
    int b = t / TPI;
    int r = t - b*TPI;
    int c = r / TPC;
    int p = (r - c*TPC)*1024 + tid*4;

    float scl = wsf[OFF_SCALE];
    int j = op[b], ap = mask[b];
    float m = ra[b];
    const float* stA = wsf + OFF_ST0 + (size_t)b * ST0;
    float mu = 0.f, lo = 0.f, hi = 0.f;
    const float* lut = nullptr;
    if (ap){
        if (j == 8)       mu = stA[0] * scl;
        else if (j == 12){ lo = stA[1+c] * scl; hi = stA[4+c] * scl; }
        else if (j == 11)  lut = stA + ((scl == 255.f) ? 784 : 16) + c*256;
    }

    float o[4];
    apply_body(x + (size_t)b*CHW, c, p, j, ap, m, scl, mu, lo, hi, lut, o);
    float4 w = {o[0], o[1], o[2], o[3]};
    *(float4*)(inter + (size_t)b*CHW + c*HWp + p) = w;

    // fused stats1 partials on outputs
    int j1 = op[NB + b], ap1 = mask[NB + b];
    bool n1 = ap1 && (j1 == 8 || j1 == 11 || j1 == 12);
    if (n1){
        const float GW[3] = {0.299f, 0.587f, 0.114f};
        if (j1 == 8){
            float s4 = (o[0] + o[1]) + (o[2] + o[3]);
            float tot = blk_reduce(s4, red, tid, 0);
            if (!tid) psum1[t] = tot * GW[c];
        } else if (j1 == 12){
            float l4 = fminf(fminf(o[0],o[1]), fminf(o[2],o[3]));
            float h4 = fmaxf(fmaxf(o[0],o[1]), fmaxf(o[2],o[3]));
            float l = blk_reduce(l4, red, tid, 1);
            if (!tid) pmin1[t] = l;
            float h = blk_reduce(h4, red, tid, 2);
            if (!tid) pmax1[t] = h;
        } else {
            sh[tid] = 0;
            __syncthreads();
            #pragma unroll
            for (int k = 0; k < 4; k++)
                atomicAdd(&sh[min(max((int)rintf(o[k]), 0), 255)], 1);
            __syncthreads();
            int v = sh[tid];
            if (v) atomicAdd(&hist1[b*768 + c*256 + tid], v);
        }
    }

    // ticket: last tile of image b finalizes stats1[b]
    __threadfence();
    __syncthreads();
    if (!tid) tk = atomicAdd(&ints[OFF_CNT1 + b], 1);
    __syncthreads();
    if (tk == TPI-1 && n1){
        __threadfence();
        float* st = wsf + OFF_ST1 + (size_t)b * ST1;
        if (j1 == 8){
            float s = 0.f;
            for (int i = tid; i < TPI; i += 256) s += psum1[b*TPI + i];
            float tot = blk_reduce(s, red, tid, 0);
            if (!tid) st[0] = tot * (1.f/(float)HWp);
        } else if (j1 == 12){
            for (int c2 = 0; c2 < 3; c2++){
                float l = (tid < TPC) ? pmin1[b*TPI + c2*TPC + tid] : 3.4e38f;
                float lr = blk_reduce(l, red, tid, 1);
                if (!tid) st[1+c2] = lr;
                float h = (tid < TPC) ? pmax1[b*TPI + c2*TPC + tid] : 0.f;
                float hr = blk_reduce(h, red, tid, 2);
                if (!tid) st[4+c2] = hr;
            }
        } else {
            for (int i = tid; i < 768; i += 256) sh[i] = hist1[b*768 + i];
            __syncthreads();
            if (tid < 3) build_lut(sh + tid*256, st + 16 + tid*256);
        }
    }
}

// ---------------- K3: apply depth 1 (inter -> out, /255 + clip) ----------------
__global__ void k3_apply1(const float* __restrict__ ra, const int* __restrict__ op,
                          const int* __restrict__ mask, float* __restrict__ out,
                          float* __restrict__ wsf)
{
    int t = blockIdx.x, tid = threadIdx.x;
    int b = t / TPI;
    int r = t - b*TPI;
    int c = r / TPC;
    int p = (r - c*TPC)*1024 + tid*4;
    const float* inter = wsf + OFF_INTER;

    int j = op[NB + b], ap = mask[NB + b];
    float m = ra[NB + b];
    const float* st = wsf + OFF_ST1 + (size_t)b * ST1;
    float mu = 0.f, lo = 0.f, hi = 0.f;
    const float* lut = nullptr;
    if (ap){
        if (j == 8)       mu = st[0];
        else if (j == 12){ lo = st[1+c]; hi = st[4+c]; }
        else if (j == 11)  lut = st + 16 + c*256;
    }

    float o[4];
    apply_body(inter + (size_t)b*CHW, c, p, j, ap, m, 1.f, mu, lo, hi, lut, o);
    float4 w;
    w.x = fminf(fmaxf(o[0]*(1.f/255.f), 0.f), 1.f);
    w.y = fminf(fmaxf(o[1]*(1.f/255.f), 0.f), 1.f);
    w.z = fminf(fmaxf(o[2]*(1.f/255.f), 0.f), 1.f);
    w.w = fminf(fmaxf(o[3]*(1.f/255.f), 0.f), 1.f);
    *(float4*)(out + (size_t)b*CHW + c*HWp + p) = w;
}

extern "C" void kernel_launch(void* const* d_in, const int* in_sizes, int n_in,
                              void* d_out, int out_size, void* d_ws, size_t ws_size,
                              hipStream_t stream) {
    const float* x    = (const float*)d_in[0];
    const float* ra   = (const float*)d_in[1];
    const int*   op   = (const int*)d_in[2];
    const int*   mask = (const int*)d_in[3];
    float* out = (float*)d_out;
    float* wsf = (float*)d_ws;

    k0_init  <<<1,    256, 0, stream>>>(wsf);
    k1_stats <<<NSL,  256, 0, stream>>>(x, op, mask, wsf);
    k2_apply0<<<NT,   256, 0, stream>>>(x, ra, op, mask, wsf);
    k3_apply1<<<NT,   256, 0, stream>>>(ra, op, mask, out, wsf);
}

// Round 9
// 149.634 us; speedup vs baseline: 7.6874x; 7.6874x over previous
//
#include <hip/hip_runtime.h>

#define WID 224
#define HGT 224
#define HWp 50176          // 224*224
#define CHW 150528         // 3*HWp
#define NB  64
#define NSL 2048           // 64 images x 32 slices
#define SCH 1568           // HWp/32
#define NT  9408           // 64*147 tiles of 1024 px
#define TPI 147            // tiles per image
#define TPC 49             // tiles per channel

// workspace offsets (4B units)
#define OFF_MAXB   0       // ints[0]: global max (float bits, atomicMax; poison is negative -> no init)
#define OFF_HIST1  256     // ints: 64*768 -> ends 49408
#define OFF_PSUM0  49408   // floats: 2048
#define OFF_PMIN0  51456   // floats: 2048*3
#define OFF_PMAX0  57600   // floats: 2048*3
#define OFF_PHIST0 63744   // ints: 2048*1536 (dual hist per slice: [0..768)=x1, [768..1536)=x255)
#define OFF_PSUM1  3209472 // floats: 9408
#define OFF_PMIN1  3218880 // floats: 9408
#define OFF_PMAX1  3228288 // floats: 9408
#define OFF_INTER  3237696 // floats: 9,633,792

__device__ __forceinline__ float clip255(float v){ return fminf(fmaxf(v, 0.f), 255.f); }

__device__ __forceinline__ float blk_reduce(float v, float* red, int tid, int op){
    red[tid] = v; __syncthreads();
    for (int s = 128; s > 0; s >>= 1){
        if (tid < s){
            float a = red[tid], b = red[tid+s];
            red[tid] = (op==0) ? a+b : (op==1 ? fminf(a,b) : fmaxf(a,b));
        }
        __syncthreads();
    }
    float r = red[0]; __syncthreads();
    return r;
}

__device__ __forceinline__ float samp(const float* __restrict__ pl, float yi, float xi, float scl){
    if (xi < 0.f || xi > (float)(WID-1) || yi < 0.f || yi > (float)(HGT-1)) return 0.f;
    return pl[(int)yi * WID + (int)xi] * scl;
}

// Parallel LUT build: shh[256] holds this channel's histogram; each thread computes one entry.
__device__ __forceinline__ void lut_from_hist(const int* shh, float* slut, int tid){
    int step = (HWp - shh[255]) / 255;
    int cum = 0;
    for (int k = 0; k < tid; k++) cum += shh[k];      // exclusive prefix (serial per thread, LDS reads)
    int l = (step > 0) ? min(max((cum + (step >> 1)) / step, 0), 255) : tid;
    slut[tid] = (float)l;
}

// Compute 4 output px for plane-offset p of channel c; stats pre-resolved.
__device__ __forceinline__ void apply_body(const float* __restrict__ img,
                                           int c, int p,
                                           int j, int ap, float m, float scl,
                                           float mu, float lo, float hi,
                                           const float* lut,
                                           float o[4])
{
    int y = p / WID;
    int x = p - y*WID;
    const float* pl = img + c*HWp;
    float4 v4 = *(const float4*)(pl + p);
    float iv[4] = {v4.x*scl, v4.y*scl, v4.z*scl, v4.w*scl};

    if (!ap) {
        #pragma unroll
        for (int k = 0; k < 4; k++) o[k] = iv[k];
        return;
    }
    switch (j){
    case 0: case 1: case 2: case 3: case 4: {   // affine family
        float a = 1.f, bb = 0.f, cc = 0.f, dd = 0.f, ee = 1.f, ff = 0.f;
        if (j == 0)      bb = -0.3f + 0.6f*m;
        else if (j == 1) dd = -0.3f + 0.6f*m;
        else if (j == 2) cc = (-0.45f + 0.9f*m) * (float)WID;
        else if (j == 3) ff = (-0.45f + 0.9f*m) * (float)HGT;
        else {
            float deg = -30.f + 60.f*m;
            float rad = deg * (float)(3.14159265358979323846/180.0);
            float cs = cosf(rad), sn = sinf(rad);
            float cx = (WID-1)*0.5f, cy = (HGT-1)*0.5f;
            a = cs; bb = sn; dd = -sn; ee = cs;
            cc = cx - cs*cx - sn*cy;
            ff = cy + sn*cx - cs*cy;
        }
        float yf = (float)y;
        #pragma unroll
        for (int k = 0; k < 4; k++){
            float xf = (float)(x + k);
            float sx = a*xf + bb*yf + cc;
            float sy = dd*xf + ee*yf + ff;
            float x0f = floorf(sx), y0f = floorf(sy);
            float wx = sx - x0f, wy = sy - y0f;
            float v00 = samp(pl, y0f,     x0f,     scl);
            float v01 = samp(pl, y0f,     x0f+1.f, scl);
            float v10 = samp(pl, y0f+1.f, x0f,     scl);
            float v11 = samp(pl, y0f+1.f, x0f+1.f, scl);
            float top = v00*(1.f-wx) + v01*wx;
            float bot = v10*(1.f-wx) + v11*wx;
            o[k] = top*(1.f-wy) + bot*wy;
        }
        break; }
    case 5: {
        float f = 0.1f + 1.8f*m;
        #pragma unroll
        for (int k = 0; k < 4; k++) o[k] = clip255(iv[k]*f);
        break; }
    case 6: {
        float4 r4 = *(const float4*)(img + p);
        float4 g4 = *(const float4*)(img + HWp + p);
        float4 b4 = *(const float4*)(img + 2*HWp + p);
        float rr[4] = {r4.x*scl, r4.y*scl, r4.z*scl, r4.w*scl};
        float gg[4] = {g4.x*scl, g4.y*scl, g4.z*scl, g4.w*scl};
        float bl[4] = {b4.x*scl, b4.y*scl, b4.z*scl, b4.w*scl};
        float f = 0.1f + 1.8f*m;
        #pragma unroll
        for (int k = 0; k < 4; k++){
            float g = 0.299f*rr[k] + 0.587f*gg[k] + 0.114f*bl[k];
            o[k] = clip255(g + f*(iv[k] - g));
        }
        break; }
    case 7: {
        float f = 0.1f + 1.8f*m;
        #pragma unroll
        for (int k = 0; k < 4; k++){
            int xx = x + k;
            if (y == 0 || y == HGT-1 || xx == 0 || xx == WID-1) o[k] = iv[k];
            else {
                int q = p + k;
                float s8 = pl[q-WID-1] + pl[q-WID] + pl[q-WID+1]
                         + pl[q-1]     + pl[q+1]
                         + pl[q+WID-1] + pl[q+WID] + pl[q+WID+1];
                float blur = (s8*scl + 5.f*iv[k]) * (1.f/13.f);
                o[k] = clip255(blur + f*(iv[k] - blur));
            }
        }
        break; }
    case 8: {
        float f = 0.1f + 1.8f*m;
        #pragma unroll
        for (int k = 0; k < 4; k++) o[k] = clip255(mu + f*(iv[k] - mu));
        break; }
    case 9: {
        float thr = 256.f*m;
        #pragma unroll
        for (int k = 0; k < 4; k++) o[k] = (iv[k] < thr) ? iv[k] : 255.f - iv[k];
        break; }
    case 10: {
        float q = exp2f(rintf(4.f*m));
        #pragma unroll
        for (int k = 0; k < 4; k++) o[k] = floorf(iv[k]/q)*q;
        break; }
    case 11: {
        #pragma unroll
        for (int k = 0; k < 4; k++){
            int ivi = min(max((int)rintf(iv[k]), 0), 255);
            o[k] = lut[ivi];
        }
        break; }
    case 12: {
        float sc = 255.f / fmaxf(hi - lo, 1e-6f);
        #pragma unroll
        for (int k = 0; k < 4; k++)
            o[k] = (hi > lo) ? clip255((iv[k] - lo) * sc) : iv[k];
        break; }
    default:
        #pragma unroll
        for (int k = 0; k < 4; k++) o[k] = iv[k];
        break;
    }
}

// ---------------- K1: slice partials over x (2048 blocks); no fences, no tickets ----------------
__global__ void k1_stats(const float* __restrict__ x, const int* __restrict__ op,
                         const int* __restrict__ mask, float* __restrict__ wsf)
{
    __shared__ float red[256];
    __shared__ int sh[1536];
    int* ints = (int*)wsf;
    float* psum0 = wsf + OFF_PSUM0;
    float* pmin0 = wsf + OFF_PMIN0;
    float* pmax0 = wsf + OFF_PMAX0;
    int* phist0 = (int*)wsf + OFF_PHIST0;
    int* hist1  = (int*)wsf + OFF_HIST1;

    int blk = blockIdx.x, tid = threadIdx.x;
    if (tid < 24) hist1[blk*24 + tid] = 0;      // zero 64*768 ints across 2048 blocks

    int b = blk >> 5, s = blk & 31;
    int j = op[b], ap = mask[b];
    bool needSum  = ap && (j == 8);
    bool needMM   = ap && (j == 12);
    bool needHist = ap && (j == 11);
    const float* img = x + (size_t)b * CHW;
    int p0 = s * SCH;
    const float GW[3] = {0.299f, 0.587f, 0.114f};

    float mx = 0.f, gs = 0.f;
    for (int c = 0; c < 3; c++){
        const float* pl = img + c*HWp + p0;
        float lo = 3.4e38f, hi = 0.f, cs = 0.f;
        for (int p = tid*4; p < SCH; p += 1024){
            float4 v = *(const float4*)(pl + p);
            float m4 = fmaxf(fmaxf(v.x, v.y), fmaxf(v.z, v.w));
            mx = fmaxf(mx, m4);
            if (needMM){ hi = fmaxf(hi, m4); lo = fminf(lo, fminf(fminf(v.x,v.y), fminf(v.z,v.w))); }
            if (needSum) cs += (v.x + v.y) + (v.z + v.w);
        }
        if (needSum) gs += GW[c] * cs;
        if (needMM){
            float l = blk_reduce(lo, red, tid, 1);
            if (!tid) pmin0[blk*3 + c] = l;
            float h = blk_reduce(hi, red, tid, 2);
            if (!tid) pmax0[blk*3 + c] = h;
        }
    }
    float bm = blk_reduce(mx, red, tid, 2);
    if (!tid) atomicMax(&ints[OFF_MAXB], __float_as_int(bm));   // bm>=0 -> int order == float order
    if (needSum){
        float t = blk_reduce(gs, red, tid, 0);
        if (!tid) psum0[blk] = t;
    }
    if (needHist){
        for (int i = tid; i < 1536; i += 256) sh[i] = 0;
        __syncthreads();
        for (int c = 0; c < 3; c++){
            const float* pl = img + c*HWp + p0;
            for (int p = tid; p < SCH; p += 256){
                float v = pl[p];
                atomicAdd(&sh[c*256 + min(max((int)rintf(v), 0), 255)], 1);
                atomicAdd(&sh[768 + c*256 + min(max((int)rintf(v*255.f), 0), 255)], 1);
            }
        }
        __syncthreads();
        for (int i = tid; i < 1536; i += 256) phist0[blk*1536 + i] = sh[i];
    }
}

// ---------------- K2: per-block finalize0 + apply depth0 + stats1 partials ----------------
__global__ void k2_apply0(const float* __restrict__ x, const float* __restrict__ ra,
                          const int* __restrict__ op, const int* __restrict__ mask,
                          float* __restrict__ wsf)
{
    __shared__ float red[256];
    __shared__ int   shh[256];
    __shared__ float slut[256];
    const int* ints = (const int*)wsf;
    const float* psum0 = wsf + OFF_PSUM0;
    const float* pmin0 = wsf + OFF_PMIN0;
    const float* pmax0 = wsf + OFF_PMAX0;
    const int* phist0 = (const int*)wsf + OFF_PHIST0;
    int* hist1 = (int*)wsf + OFF_HIST1;
    float* psum1 = wsf + OFF_PSUM1;
    float* pmin1 = wsf + OFF_PMIN1;
    float* pmax1 = wsf + OFF_PMAX1;
    float* inter = wsf + OFF_INTER;

    int t = blockIdx.x, tid = threadIdx.x;
    int b = t / TPI;
    int r = t - b*TPI;
    int c = r / TPC;
    int p = (r - c*TPC)*1024 + tid*4;

    float scl = (__int_as_float(ints[OFF_MAXB]) <= 1.0f) ? 255.f : 1.f;
    int j = op[b], ap = mask[b];
    float m = ra[b];

    // per-block finalize of stats0 (cheap, redundant across the image's blocks)
    float mu = 0.f, lo = 0.f, hi = 0.f;
    const float* lut = nullptr;
    if (ap){
        if (j == 8){
            float v = (tid < 32) ? psum0[b*32 + tid] : 0.f;
            mu = blk_reduce(v, red, tid, 0) * scl * (1.f/(float)HWp);
        } else if (j == 12){
            float v  = (tid < 32) ? pmin0[(b*32 + tid)*3 + c] : 3.4e38f;
            lo = blk_reduce(v, red, tid, 1) * scl;
            float v2 = (tid < 32) ? pmax0[(b*32 + tid)*3 + c] : 0.f;
            hi = blk_reduce(v2, red, tid, 2) * scl;
        } else if (j == 11){
            int d = (scl == 255.f) ? 1 : 0;
            const int* ph = phist0 + d*768 + c*256 + tid;
            int sum = 0;
            #pragma unroll 8
            for (int s = 0; s < 32; s++) sum += ph[(b*32 + s)*1536];
            shh[tid] = sum;
            __syncthreads();
            lut_from_hist(shh, slut, tid);
            __syncthreads();
            lut = slut;
        }
    }

    float o[4];
    apply_body(x + (size_t)b*CHW, c, p, j, ap, m, scl, mu, lo, hi, lut, o);
    float4 w = {o[0], o[1], o[2], o[3]};
    *(float4*)(inter + (size_t)b*CHW + c*HWp + p) = w;

    // fused stats1 partials on outputs (plain per-block-slot stores; K3 sees them via kernel boundary)
    int j1 = op[NB + b], ap1 = mask[NB + b];
    if (ap1 && (j1 == 8 || j1 == 11 || j1 == 12)){
        const float GW[3] = {0.299f, 0.587f, 0.114f};
        if (j1 == 8){
            float s4 = (o[0] + o[1]) + (o[2] + o[3]);
            float tot = blk_reduce(s4, red, tid, 0);
            if (!tid) psum1[t] = tot * GW[c];
        } else if (j1 == 12){
            float l4 = fminf(fminf(o[0],o[1]), fminf(o[2],o[3]));
            float h4 = fmaxf(fmaxf(o[0],o[1]), fmaxf(o[2],o[3]));
            float l = blk_reduce(l4, red, tid, 1);
            if (!tid) pmin1[t] = l;
            float h = blk_reduce(h4, red, tid, 2);
            if (!tid) pmax1[t] = h;
        } else {
            __syncthreads();              // shh may have been read above; safe to reuse
            shh[tid] = 0;
            __syncthreads();
            #pragma unroll
            for (int k = 0; k < 4; k++)
                atomicAdd(&shh[min(max((int)rintf(o[k]), 0), 255)], 1);
            __syncthreads();
            int v = shh[tid];
            if (v) atomicAdd(&hist1[b*768 + c*256 + tid], v);
        }
    }
}

// ---------------- K3: per-block finalize1 + apply depth1 -> out ----------------
__global__ void k3_apply1(const float* __restrict__ ra, const int* __restrict__ op,
                          const int* __restrict__ mask, float* __restrict__ out,
                          float* __restrict__ wsf)
{
    __shared__ float red[256];
    __shared__ int   shh[256];
    __shared__ float slut[256];
    const int* hist1 = (const int*)wsf + OFF_HIST1;
    const float* psum1 = wsf + OFF_PSUM1;
    const float* pmin1 = wsf + OFF_PMIN1;
    const float* pmax1 = wsf + OFF_PMAX1;
    const float* inter = wsf + OFF_INTER;

    int t = blockIdx.x, tid = threadIdx.x;
    int b = t / TPI;
    int r = t - b*TPI;
    int c = r / TPC;
    int p = (r - c*TPC)*1024 + tid*4;

    int j = op[NB + b], ap = mask[NB + b];
    float m = ra[NB + b];

    float mu = 0.f, lo = 0.f, hi = 0.f;
    const float* lut = nullptr;
    if (ap){
        if (j == 8){
            float v = (tid < TPI) ? psum1[b*TPI + tid] : 0.f;
            mu = blk_reduce(v, red, tid, 0) * (1.f/(float)HWp);
        } else if (j == 12){
            float v  = (tid < TPC) ? pmin1[b*TPI + c*TPC + tid] : 3.4e38f;
            lo = blk_reduce(v, red, tid, 1);
            float v2 = (tid < TPC) ? pmax1[b*TPI + c*TPC + tid] : 0.f;
            hi = blk_reduce(v2, red, tid, 2);
        } else if (j == 11){
            shh[tid] = hist1[b*768 + c*256 + tid];
            __syncthreads();
            lut_from_hist(shh, slut, tid);
            __syncthreads();
            lut = slut;
        }
    }

    float o[4];
    apply_body(inter + (size_t)b*CHW, c, p, j, ap, m, 1.f, mu, lo, hi, lut, o);
    float4 w;
    w.x = fminf(fmaxf(o[0]*(1.f/255.f), 0.f), 1.f);
    w.y = fminf(fmaxf(o[1]*(1.f/255.f), 0.f), 1.f);
    w.z = fminf(fmaxf(o[2]*(1.f/255.f), 0.f), 1.f);
    w.w = fminf(fmaxf(o[3]*(1.f/255.f), 0.f), 1.f);
    *(float4*)(out + (size_t)b*CHW + c*HWp + p) = w;
}

extern "C" void kernel_launch(void* const* d_in, const int* in_sizes, int n_in,
                              void* d_out, int out_size, void* d_ws, size_t ws_size,
                              hipStream_t stream) {
    const float* x    = (const float*)d_in[0];
    const float* ra   = (const float*)d_in[1];
    const int*   op   = (const int*)d_in[2];
    const int*   mask = (const int*)d_in[3];
    float* out = (float*)d_out;
    float* wsf = (float*)d_ws;

    k1_stats <<<NSL, 256, 0, stream>>>(x, op, mask, wsf);
    k2_apply0<<<NT,  256, 0, stream>>>(x, ra, op, mask, wsf);
    k3_apply1<<<NT,  256, 0, stream>>>(ra, op, mask, out, wsf);
}